// Round 1
// baseline (1215.863 us; speedup 1.0000x reference)
//
#include <hip/hip_runtime.h>
#include <math.h>

typedef unsigned short u16;
typedef unsigned int u32;
typedef __attribute__((ext_vector_type(8))) __bf16 bf16x8;
typedef __attribute__((ext_vector_type(4))) float f32x4;
typedef __attribute__((ext_vector_type(8))) u16 u16x8;
typedef __attribute__((ext_vector_type(4))) u16 u16x4;

#define BB 2
#define SS 2048
#define HH 2048
#define NHH 16
#define DD 128
#define FFF 8192
#define MM (BB * SS)

__device__ __forceinline__ u16 f2bf(float f) {
  u32 u = __float_as_uint(f);
  u32 r = (u + 0x7FFFu + ((u >> 16) & 1u)) >> 16;
  return (u16)r;
}
__device__ __forceinline__ float b2f(u16 h) {
  return __uint_as_float(((u32)h) << 16);
}
__device__ __forceinline__ void gll16(const void* g, void* l) {
  __builtin_amdgcn_global_load_lds((const __attribute__((address_space(1))) void*)g,
                                   (__attribute__((address_space(3))) void*)l, 16, 0, 0);
}

// ---------------- fp32 -> bf16 convert (weights) ----------------
__global__ __launch_bounds__(256) void cvt_bf16(const float* __restrict__ in,
                                                u16* __restrict__ out, int n) {
  int i = (blockIdx.x * 256 + threadIdx.x) * 4;
  if (i + 3 < n) {
    f32x4 v = *(const f32x4*)(in + i);
    u16x4 o;
    o[0] = f2bf(v[0]); o[1] = f2bf(v[1]); o[2] = f2bf(v[2]); o[3] = f2bf(v[3]);
    *(u16x4*)(out + i) = o;
  }
}

// ---------------- LayerNorm (fp32 in, bf16 out) ----------------
__global__ __launch_bounds__(256) void ln_bf16(const float* __restrict__ x,
                                               const float* __restrict__ w,
                                               const float* __restrict__ bsh,
                                               u16* __restrict__ out) {
  const int row = blockIdx.x, tid = threadIdx.x;
  const float* xr = x + (size_t)row * HH;
  f32x4 a = ((const f32x4*)xr)[tid * 2];
  f32x4 b = ((const f32x4*)xr)[tid * 2 + 1];
  float s = a[0] + a[1] + a[2] + a[3] + b[0] + b[1] + b[2] + b[3];
  float q = a[0]*a[0] + a[1]*a[1] + a[2]*a[2] + a[3]*a[3]
          + b[0]*b[0] + b[1]*b[1] + b[2]*b[2] + b[3]*b[3];
#pragma unroll
  for (int off = 32; off > 0; off >>= 1) {
    s += __shfl_down(s, off);
    q += __shfl_down(q, off);
  }
  __shared__ float red[8];
  const int wave = tid >> 6;
  if ((tid & 63) == 0) { red[wave] = s; red[4 + wave] = q; }
  __syncthreads();
  s = red[0] + red[1] + red[2] + red[3];
  q = red[4] + red[5] + red[6] + red[7];
  const float mean = s * (1.0f / HH);
  const float var = q * (1.0f / HH) - mean * mean;
  const float rstd = 1.0f / sqrtf(var + 1e-5f);
  f32x4 w0 = ((const f32x4*)w)[tid * 2];
  f32x4 w1 = ((const f32x4*)w)[tid * 2 + 1];
  f32x4 b0 = ((const f32x4*)bsh)[tid * 2];
  f32x4 b1 = ((const f32x4*)bsh)[tid * 2 + 1];
  u16x8 o;
#pragma unroll
  for (int i = 0; i < 4; ++i) o[i] = f2bf((a[i] - mean) * rstd * w0[i] + b0[i]);
#pragma unroll
  for (int i = 0; i < 4; ++i) o[4 + i] = f2bf((b[i] - mean) * rstd * w1[i] + b1[i]);
  *(u16x8*)(out + (size_t)row * HH + tid * 8) = o;
}

// ---------------- GEMM: C[M,N] = A[M,K](bf16) * B^T[N,K](bf16) + epilogue ----------------
// MODE 0: +bias, write bf16. MODE 1: +bias+resid(f32), write f32. MODE 2: +bias, gelu, write bf16.
template <int MODE>
__global__ __launch_bounds__(256) void gemm_bt(const u16* __restrict__ A,
                                               const u16* __restrict__ Bw,
                                               const float* __restrict__ bias,
                                               const float* resid, void* Cout,
                                               int M, int N, int K) {
  __shared__ __align__(16) u16 As[128 * 64];
  __shared__ __align__(16) u16 Bs[128 * 64];
  const int tid = threadIdx.x;
  const int wave = tid >> 6, lane = tid & 63;
  const int l15 = lane & 15, quad = lane >> 4;
  const int bm = blockIdx.x, bn = blockIdx.y;
  const int wm = (wave >> 1) << 6, wn = (wave & 1) << 6;

  f32x4 acc[4][4] = {};

  const int srow = (wave << 5) + (lane >> 3);
  const int sg = (lane & 7) ^ (lane >> 3);
  const u16* aptr = A + (size_t)(bm * 128 + srow) * K + sg * 8;
  const u16* bptr = Bw + (size_t)(bn * 128 + srow) * K + sg * 8;

  const int nk = K >> 6;
  for (int kt = 0; kt < nk; ++kt) {
#pragma unroll
    for (int i = 0; i < 4; ++i)
      gll16(aptr + (size_t)i * 8 * K, &As[(wave * 4 + i) * 512]);
#pragma unroll
    for (int i = 0; i < 4; ++i)
      gll16(bptr + (size_t)i * 8 * K, &Bs[(wave * 4 + i) * 512]);
    aptr += 64; bptr += 64;
    __syncthreads();
#pragma unroll
    for (int t = 0; t < 2; ++t) {
      bf16x8 af[4], bfv[4];
#pragma unroll
      for (int i = 0; i < 4; ++i) {
        const int m = wm + i * 16 + l15;
        const int n = wn + i * 16 + l15;
        const int gi = t * 4 + quad;
        af[i] = *(const bf16x8*)&As[m * 64 + ((gi ^ (m & 7)) << 3)];
        bfv[i] = *(const bf16x8*)&Bs[n * 64 + ((gi ^ (n & 7)) << 3)];
      }
#pragma unroll
      for (int i = 0; i < 4; ++i)
#pragma unroll
        for (int j = 0; j < 4; ++j)
          acc[i][j] = __builtin_amdgcn_mfma_f32_16x16x32_bf16(af[i], bfv[j], acc[i][j], 0, 0, 0);
    }
    __syncthreads();
  }

#pragma unroll
  for (int i = 0; i < 4; ++i) {
    const int row0 = bm * 128 + wm + i * 16 + quad * 4;
#pragma unroll
    for (int j = 0; j < 4; ++j) {
      const int col = bn * 128 + wn + j * 16 + l15;
      const float bv = bias[col];
#pragma unroll
      for (int r = 0; r < 4; ++r) {
        const size_t idx = (size_t)(row0 + r) * N + col;
        float v = acc[i][j][r] + bv;
        if constexpr (MODE == 0) {
          ((u16*)Cout)[idx] = f2bf(v);
        } else if constexpr (MODE == 1) {
          ((float*)Cout)[idx] = v + resid[idx];
        } else {
          v = 0.5f * v * (1.0f + erff(v * 0.70710678118654752f));
          ((u16*)Cout)[idx] = f2bf(v);
        }
      }
    }
  }
}

// ---------------- RoPE + QKV rearrange: [B,S,NH,3D] -> Qr/Kr/V [B,NH,S,D] ----------------
__global__ __launch_bounds__(256) void rope_kernel(const u16* __restrict__ qkv,
                                                   u16* __restrict__ Qr,
                                                   u16* __restrict__ Kr,
                                                   u16* __restrict__ Vr) {
  const int tid = threadIdx.x;
  const int d = tid & 63;
  const int s = blockIdx.x * 4 + (tid >> 6);
  const int h = blockIdx.y, b = blockIdx.z;
  const u16* row = qkv + ((size_t)(b * SS + s)) * (3 * HH) + h * (3 * DD);
  const float q1 = b2f(row[d]),        q2 = b2f(row[d + 64]);
  const float k1 = b2f(row[DD + d]),   k2 = b2f(row[DD + d + 64]);
  // inv_freq = 10000^(-d/64) = exp(-d * ln(10000)/64)
  const float inv = expf((float)d * -0.14391156830963714f);
  const float ang = (float)s * inv;
  const float cs = cosf(ang), sn = sinf(ang);
  const size_t o = ((size_t)(b * NHH + h) * SS + s) * DD;
  Qr[o + d]      = f2bf(q1 * cs - q2 * sn);
  Qr[o + d + 64] = f2bf(q2 * cs + q1 * sn);
  Kr[o + d]      = f2bf(k1 * cs - k2 * sn);
  Kr[o + d + 64] = f2bf(k2 * cs + k1 * sn);
  Vr[o + d]      = row[2 * DD + d];
  Vr[o + d + 64] = row[2 * DD + d + 64];
}

// ---------------- causal flash attention (bf16 MFMA, fp32 online softmax) ----------------
__global__ __launch_bounds__(256) void attn_kernel(const u16* __restrict__ Q,
                                                   const u16* __restrict__ Kg,
                                                   const u16* __restrict__ Vg,
                                                   u16* __restrict__ ctx) {
  __shared__ __align__(16) u16 Ks[64 * 128];   // [key][d], 16-chunk swizzle per row
  __shared__ __align__(16) u16 Vt[128 * 64];   // [d][key], 8-chunk swizzle per row
  __shared__ __align__(16) u16 Ps[4][16 * 64]; // per-wave P, 8-chunk swizzle per row
  const int tid = threadIdx.x;
  const int wave = tid >> 6, lane = tid & 63;
  const int l15 = lane & 15, quad = lane >> 4;
  const int qi = blockIdx.x, h = blockIdx.y, b = blockIdx.z;
  const size_t bh_off = ((size_t)(b * NHH + h)) * (SS * DD);
  const u16* Qp = Q + bh_off;
  const u16* Kp = Kg + bh_off;
  const u16* Vp = Vg + bh_off;
  const int q0 = qi * 64;

  bf16x8 qf[4];
  {
    const u16* qr = Qp + (size_t)(q0 + wave * 16 + l15) * DD + quad * 8;
#pragma unroll
    for (int t = 0; t < 4; ++t) qf[t] = *(const bf16x8*)(qr + t * 32);
  }

  f32x4 oacc[8] = {};
  float m_run[4] = {-3e38f, -3e38f, -3e38f, -3e38f};
  float l_run[4] = {0.f, 0.f, 0.f, 0.f};

  for (int kt = 0; kt <= qi; ++kt) {
    const int k0 = kt * 64;
    // stage K tile (async direct-to-LDS), rows of 256B = 16 chunks, swizzled
#pragma unroll
    for (int i = 0; i < 4; ++i) {
      const int r = (wave * 4 + i) * 4 + quad;
      const int gg = l15 ^ (r & 15);
      gll16(Kp + (size_t)(k0 + r) * DD + gg * 8, &Ks[(wave * 4 + i) * 512]);
    }
    // stage V transposed: Vt[d][key], packed key-pairs as dwords, swizzled
#pragma unroll
    for (int s2 = 0; s2 < 2; ++s2) {
      const int task = tid + s2 * 256;     // 0..511
      const int kp = task & 31;            // key pair index
      const int db = task >> 5;            // d block (8 wide)
      const u16* v0 = Vp + (size_t)(k0 + kp * 2) * DD + db * 8;
      u16x8 va = *(const u16x8*)v0;
      u16x8 vb = *(const u16x8*)(v0 + DD);
#pragma unroll
      for (int e = 0; e < 8; ++e) {
        const int d = db * 8 + e;
        const u32 pk = (u32)va[e] | ((u32)vb[e] << 16);
        ((u32*)Vt)[d * 32 + (((kp >> 2) ^ (d & 7)) << 2) + (kp & 3)] = pk;
      }
    }
    __syncthreads();

    // S = Q * K^T
    f32x4 sacc[4] = {};
#pragma unroll
    for (int t = 0; t < 4; ++t) {
#pragma unroll
      for (int jt = 0; jt < 4; ++jt) {
        const int key = jt * 16 + l15;
        const int gg = t * 4 + quad;
        bf16x8 kf = *(const bf16x8*)&Ks[key * 128 + ((gg ^ (key & 15)) << 3)];
        sacc[jt] = __builtin_amdgcn_mfma_f32_16x16x32_bf16(qf[t], kf, sacc[jt], 0, 0, 0);
      }
    }

    const float scale = 0.08838834764831845f;  // 1/sqrt(128)
    float pv[4][4];
    float mx[4] = {-3e38f, -3e38f, -3e38f, -3e38f};
    const int qrow0 = q0 + wave * 16 + quad * 4;
#pragma unroll
    for (int jt = 0; jt < 4; ++jt)
#pragma unroll
      for (int r = 0; r < 4; ++r) {
        float sv = sacc[jt][r] * scale;
        if (kt == qi) {
          const int key = k0 + jt * 16 + l15;
          if (key > qrow0 + r) sv = -3e38f;
        }
        pv[jt][r] = sv;
        mx[r] = fmaxf(mx[r], sv);
      }
#pragma unroll
    for (int r = 0; r < 4; ++r) {
      mx[r] = fmaxf(mx[r], __shfl_xor(mx[r], 1));
      mx[r] = fmaxf(mx[r], __shfl_xor(mx[r], 2));
      mx[r] = fmaxf(mx[r], __shfl_xor(mx[r], 4));
      mx[r] = fmaxf(mx[r], __shfl_xor(mx[r], 8));
    }
    float alpha[4], mnew[4];
#pragma unroll
    for (int r = 0; r < 4; ++r) {
      mnew[r] = fmaxf(m_run[r], mx[r]);
      alpha[r] = __expf(m_run[r] - mnew[r]);
      m_run[r] = mnew[r];
    }
    float rs[4] = {0.f, 0.f, 0.f, 0.f};
#pragma unroll
    for (int jt = 0; jt < 4; ++jt)
#pragma unroll
      for (int r = 0; r < 4; ++r) {
        const float p = __expf(pv[jt][r] - mnew[r]);
        pv[jt][r] = p;
        rs[r] += p;
      }
#pragma unroll
    for (int r = 0; r < 4; ++r) {
      rs[r] += __shfl_xor(rs[r], 1);
      rs[r] += __shfl_xor(rs[r], 2);
      rs[r] += __shfl_xor(rs[r], 4);
      rs[r] += __shfl_xor(rs[r], 8);
      l_run[r] = l_run[r] * alpha[r] + rs[r];
    }
#pragma unroll
    for (int jn = 0; jn < 8; ++jn)
#pragma unroll
      for (int r = 0; r < 4; ++r) oacc[jn][r] *= alpha[r];

    // P: C-layout -> LDS (bf16), row = q (16), 64 keys, swizzled chunks
#pragma unroll
    for (int jt = 0; jt < 4; ++jt)
#pragma unroll
      for (int r = 0; r < 4; ++r) {
        const int qr = quad * 4 + r;
        const int key = jt * 16 + l15;
        Ps[wave][qr * 64 + (((key >> 3) ^ (qr & 7)) << 3) + (key & 7)] = f2bf(pv[jt][r]);
      }
    __threadfence_block();  // order same-wave cross-lane LDS RAW (Ps write -> Ps read)

    // O += P * V
#pragma unroll
    for (int t = 0; t < 2; ++t) {
      const int gg = t * 4 + quad;
      bf16x8 pf = *(const bf16x8*)&Ps[wave][l15 * 64 + ((gg ^ (l15 & 7)) << 3)];
#pragma unroll
      for (int jn = 0; jn < 8; ++jn) {
        const int nd = jn * 16 + l15;
        bf16x8 vf = *(const bf16x8*)&Vt[nd * 64 + ((gg ^ (nd & 7)) << 3)];
        oacc[jn] = __builtin_amdgcn_mfma_f32_16x16x32_bf16(pf, vf, oacc[jn], 0, 0, 0);
      }
    }
    __syncthreads();
  }

#pragma unroll
  for (int jn = 0; jn < 8; ++jn)
#pragma unroll
    for (int r = 0; r < 4; ++r) {
      const int qrow = q0 + wave * 16 + quad * 4 + r;
      const float ov = oacc[jn][r] / l_run[r];
      ctx[((size_t)(b * SS + qrow)) * HH + h * DD + jn * 16 + l15] = f2bf(ov);
    }
}

// ---------------- launch ----------------
extern "C" void kernel_launch(void* const* d_in, const int* in_sizes, int n_in,
                              void* d_out, int out_size, void* d_ws, size_t ws_size,
                              hipStream_t stream) {
  (void)in_sizes; (void)n_in; (void)ws_size;
  const float* hidden = (const float*)d_in[0];
  const float* ln1w = (const float*)d_in[2];
  const float* ln1b = (const float*)d_in[3];
  const float* wqkv = (const float*)d_in[4];
  const float* bqkv = (const float*)d_in[5];
  const float* wdense = (const float*)d_in[6];
  const float* bdense = (const float*)d_in[7];
  const float* ln2w = (const float*)d_in[8];
  const float* ln2b = (const float*)d_in[9];
  const float* w1 = (const float*)d_in[10];
  const float* b1 = (const float*)d_in[11];
  const float* w2 = (const float*)d_in[12];
  const float* b2 = (const float*)d_in[13];

  char* ws = (char*)d_ws;
  size_t off = 0;
  auto alloc = [&](size_t elems) {
    u16* p = (u16*)(ws + off);
    off += ((elems * 2 + 255) & ~(size_t)255);
    return p;
  };
  u16* wqkvbf = alloc((size_t)3 * HH * HH);     // 12.6M elems
  u16* wdbf   = alloc((size_t)HH * HH);         // 4.2M
  u16* w1bf   = alloc((size_t)FFF * HH);        // 16.8M
  u16* w2bf   = alloc((size_t)HH * FFF);        // 16.8M
  u16* xbf    = alloc((size_t)MM * HH);         // x / x2 (LN outputs)
  u16* ctx    = alloc((size_t)MM * HH);
  u16* big    = alloc((size_t)MM * 3 * HH + 3 * (size_t)BB * NHH * SS * DD);
  u16* qkvbuf = big;                             // [4096, 6144]
  u16* Qr = big + (size_t)MM * 3 * HH;
  u16* Kr = Qr + (size_t)BB * NHH * SS * DD;
  u16* Vr = Kr + (size_t)BB * NHH * SS * DD;
  u16* inter = big;                              // [4096, 8192] aliases qkv+Qr (dead by then)

  // weight conversions (every call: ws is re-poisoned by harness)
  cvt_bf16<<<(3 * HH * HH) / 1024, 256, 0, stream>>>(wqkv, wqkvbf, 3 * HH * HH);
  cvt_bf16<<<(HH * HH) / 1024, 256, 0, stream>>>(wdense, wdbf, HH * HH);
  cvt_bf16<<<(FFF * HH) / 1024, 256, 0, stream>>>(w1, w1bf, FFF * HH);
  cvt_bf16<<<(HH * FFF) / 1024, 256, 0, stream>>>(w2, w2bf, HH * FFF);

  // LN1
  ln_bf16<<<MM, 256, 0, stream>>>(hidden, ln1w, ln1b, xbf);
  // QKV GEMM
  gemm_bt<0><<<dim3(MM / 128, (3 * HH) / 128), 256, 0, stream>>>(
      xbf, wqkvbf, bqkv, nullptr, qkvbuf, MM, 3 * HH, HH);
  // RoPE + rearrange
  rope_kernel<<<dim3(SS / 4, NHH, BB), 256, 0, stream>>>(qkvbuf, Qr, Kr, Vr);
  // attention
  attn_kernel<<<dim3(SS / 64, NHH, BB), 256, 0, stream>>>(Qr, Kr, Vr, ctx);
  // dense + residual -> d_out (fp32 hidden2)
  gemm_bt<1><<<dim3(MM / 128, HH / 128), 256, 0, stream>>>(
      ctx, wdbf, bdense, hidden, d_out, MM, HH, HH);
  // LN2
  ln_bf16<<<MM, 256, 0, stream>>>((const float*)d_out, ln2w, ln2b, xbf);
  // FF1 + GELU
  gemm_bt<2><<<dim3(MM / 128, FFF / 128), 256, 0, stream>>>(
      xbf, w1bf, b1, nullptr, inter, MM, FFF, HH);
  // FF2 + residual (in-place on d_out)
  gemm_bt<1><<<dim3(MM / 128, HH / 128), 256, 0, stream>>>(
      inter, w2bf, b2, (const float*)d_out, d_out, MM, HH, FFF);

  // attention_mask output (all-False -> zeros), tail of d_out
  const size_t hid_elems = (size_t)MM * HH;
  if ((size_t)out_size > hid_elems)
    hipMemsetAsync((char*)d_out + hid_elems * 4, 0,
                   ((size_t)out_size - hid_elems) * 4, stream);
}

// Round 2
// 952.487 us; speedup vs baseline: 1.2765x; 1.2765x over previous
//
#include <hip/hip_runtime.h>
#include <math.h>

typedef unsigned short u16;
typedef unsigned int u32;
typedef __attribute__((ext_vector_type(8))) __bf16 bf16x8;
typedef __attribute__((ext_vector_type(4))) float f32x4;
typedef __attribute__((ext_vector_type(8))) u16 u16x8;
typedef __attribute__((ext_vector_type(4))) u16 u16x4;

#define BB 2
#define SS 2048
#define HH 2048
#define NHH 16
#define DD 128
#define FFF 8192
#define MM (BB * SS)

__device__ __forceinline__ u16 f2bf(float f) {
  u32 u = __float_as_uint(f);
  u32 r = (u + 0x7FFFu + ((u >> 16) & 1u)) >> 16;
  return (u16)r;
}
__device__ __forceinline__ float b2f(u16 h) {
  return __uint_as_float(((u32)h) << 16);
}
__device__ __forceinline__ void gll16(const void* g, void* l) {
  __builtin_amdgcn_global_load_lds((const __attribute__((address_space(1))) void*)g,
                                   (__attribute__((address_space(3))) void*)l, 16, 0, 0);
}

// ---------------- fp32 -> bf16 convert (weights) ----------------
__global__ __launch_bounds__(256) void cvt_bf16(const float* __restrict__ in,
                                                u16* __restrict__ out, int n) {
  int i = (blockIdx.x * 256 + threadIdx.x) * 4;
  if (i + 3 < n) {
    f32x4 v = *(const f32x4*)(in + i);
    u16x4 o;
    o[0] = f2bf(v[0]); o[1] = f2bf(v[1]); o[2] = f2bf(v[2]); o[3] = f2bf(v[3]);
    *(u16x4*)(out + i) = o;
  }
}

// ---------------- LayerNorm (fp32 in, bf16 out) ----------------
__global__ __launch_bounds__(256) void ln_bf16(const float* __restrict__ x,
                                               const float* __restrict__ w,
                                               const float* __restrict__ bsh,
                                               u16* __restrict__ out) {
  const int row = blockIdx.x, tid = threadIdx.x;
  const float* xr = x + (size_t)row * HH;
  f32x4 a = ((const f32x4*)xr)[tid * 2];
  f32x4 b = ((const f32x4*)xr)[tid * 2 + 1];
  float s = a[0] + a[1] + a[2] + a[3] + b[0] + b[1] + b[2] + b[3];
  float q = a[0]*a[0] + a[1]*a[1] + a[2]*a[2] + a[3]*a[3]
          + b[0]*b[0] + b[1]*b[1] + b[2]*b[2] + b[3]*b[3];
#pragma unroll
  for (int off = 32; off > 0; off >>= 1) {
    s += __shfl_down(s, off);
    q += __shfl_down(q, off);
  }
  __shared__ float red[8];
  const int wave = tid >> 6;
  if ((tid & 63) == 0) { red[wave] = s; red[4 + wave] = q; }
  __syncthreads();
  s = red[0] + red[1] + red[2] + red[3];
  q = red[4] + red[5] + red[6] + red[7];
  const float mean = s * (1.0f / HH);
  const float var = q * (1.0f / HH) - mean * mean;
  const float rstd = 1.0f / sqrtf(var + 1e-5f);
  f32x4 w0 = ((const f32x4*)w)[tid * 2];
  f32x4 w1 = ((const f32x4*)w)[tid * 2 + 1];
  f32x4 b0 = ((const f32x4*)bsh)[tid * 2];
  f32x4 b1 = ((const f32x4*)bsh)[tid * 2 + 1];
  u16x8 o;
#pragma unroll
  for (int i = 0; i < 4; ++i) o[i] = f2bf((a[i] - mean) * rstd * w0[i] + b0[i]);
#pragma unroll
  for (int i = 0; i < 4; ++i) o[4 + i] = f2bf((b[i] - mean) * rstd * w1[i] + b1[i]);
  *(u16x8*)(out + (size_t)row * HH + tid * 8) = o;
}

// ---------------- GEMM: C[M,N] = A[M,K](bf16) * B^T[N,K](bf16) + epilogue ----------------
template <int MODE>
__global__ __launch_bounds__(256) void gemm_bt(const u16* __restrict__ A,
                                               const u16* __restrict__ Bw,
                                               const float* __restrict__ bias,
                                               const float* resid, void* Cout,
                                               int M, int N, int K) {
  __shared__ __align__(16) u16 As[128 * 64];
  __shared__ __align__(16) u16 Bs[128 * 64];
  const int tid = threadIdx.x;
  const int wave = tid >> 6, lane = tid & 63;
  const int l15 = lane & 15, quad = lane >> 4;
  const int bm = blockIdx.x, bn = blockIdx.y;
  const int wm = (wave >> 1) << 6, wn = (wave & 1) << 6;

  f32x4 acc[4][4] = {};

  const int srow = (wave << 5) + (lane >> 3);
  const int sg = (lane & 7) ^ (lane >> 3);
  const u16* aptr = A + (size_t)(bm * 128 + srow) * K + sg * 8;
  const u16* bptr = Bw + (size_t)(bn * 128 + srow) * K + sg * 8;

  const int nk = K >> 6;
  for (int kt = 0; kt < nk; ++kt) {
#pragma unroll
    for (int i = 0; i < 4; ++i)
      gll16(aptr + (size_t)i * 8 * K, &As[(wave * 4 + i) * 512]);
#pragma unroll
    for (int i = 0; i < 4; ++i)
      gll16(bptr + (size_t)i * 8 * K, &Bs[(wave * 4 + i) * 512]);
    aptr += 64; bptr += 64;
    __syncthreads();
#pragma unroll
    for (int t = 0; t < 2; ++t) {
      bf16x8 af[4], bfv[4];
#pragma unroll
      for (int i = 0; i < 4; ++i) {
        const int m = wm + i * 16 + l15;
        const int n = wn + i * 16 + l15;
        const int gi = t * 4 + quad;
        af[i] = *(const bf16x8*)&As[m * 64 + ((gi ^ (m & 7)) << 3)];
        bfv[i] = *(const bf16x8*)&Bs[n * 64 + ((gi ^ (n & 7)) << 3)];
      }
#pragma unroll
      for (int i = 0; i < 4; ++i)
#pragma unroll
        for (int j = 0; j < 4; ++j)
          acc[i][j] = __builtin_amdgcn_mfma_f32_16x16x32_bf16(af[i], bfv[j], acc[i][j], 0, 0, 0);
    }
    __syncthreads();
  }

#pragma unroll
  for (int i = 0; i < 4; ++i) {
    const int row0 = bm * 128 + wm + i * 16 + quad * 4;
#pragma unroll
    for (int j = 0; j < 4; ++j) {
      const int col = bn * 128 + wn + j * 16 + l15;
      const float bv = bias[col];
#pragma unroll
      for (int r = 0; r < 4; ++r) {
        const size_t idx = (size_t)(row0 + r) * N + col;
        float v = acc[i][j][r] + bv;
        if constexpr (MODE == 0) {
          ((u16*)Cout)[idx] = f2bf(v);
        } else if constexpr (MODE == 1) {
          ((float*)Cout)[idx] = v + resid[idx];
        } else {
          v = 0.5f * v * (1.0f + erff(v * 0.70710678118654752f));
          ((u16*)Cout)[idx] = f2bf(v);
        }
      }
    }
  }
}

// ---------------- RoPE: qkv [B,S,NH*3D] -> Qr/Kr [B,NH,S,D] ----------------
__global__ __launch_bounds__(256) void rope_kernel(const u16* __restrict__ qkv,
                                                   u16* __restrict__ Qr,
                                                   u16* __restrict__ Kr) {
  const int tid = threadIdx.x;
  const int d = tid & 63;
  const int s = blockIdx.x * 4 + (tid >> 6);
  const int h = blockIdx.y, b = blockIdx.z;
  const u16* row = qkv + ((size_t)(b * SS + s)) * (3 * HH) + h * (3 * DD);
  const float q1 = b2f(row[d]),        q2 = b2f(row[d + 64]);
  const float k1 = b2f(row[DD + d]),   k2 = b2f(row[DD + d + 64]);
  const float inv = expf((float)d * -0.14391156830963714f);
  const float ang = (float)s * inv;
  const float cs = cosf(ang), sn = sinf(ang);
  const size_t o = ((size_t)(b * NHH + h) * SS + s) * DD;
  Qr[o + d]      = f2bf(q1 * cs - q2 * sn);
  Qr[o + d + 64] = f2bf(q2 * cs + q1 * sn);
  Kr[o + d]      = f2bf(k1 * cs - k2 * sn);
  Kr[o + d + 64] = f2bf(k2 * cs + k1 * sn);
}

// ---------------- V transpose: qkv V-slice -> Vt_g [B*NH, D, S] ----------------
__device__ __forceinline__ int vslot(int s, int chunk) {
  return chunk ^ (s & 7) ^ ((s >> 3) & 7);
}
__global__ __launch_bounds__(256) void vtrans(const u16* __restrict__ qkv,
                                              u16* __restrict__ Vt) {
  __shared__ __align__(16) u16 Vs[64 * 128];
  const int tid = threadIdx.x;
  const int s0 = blockIdx.x * 64;
  const int bh = blockIdx.y;
  const int b = bh >> 4, h = bh & 15;
  const u16* src = qkv + (size_t)(b * SS + s0) * (3 * HH) + h * (3 * DD) + 2 * DD;
#pragma unroll
  for (int rr = 0; rr < 4; ++rr) {
    const int task = tid + rr * 256;
    const int sr = task >> 4, c = task & 15;
    u16x8 v = *(const u16x8*)(src + (size_t)sr * (3 * HH) + c * 8);
    // store d-chunks swizzled: 16 chunks of 8 -> slot uses low 3 bits only, pair c,c^8 kept distinct via bit3
    const int sl = (vslot(sr, c & 7) | (c & 8));
    *(u16x8*)&Vs[sr * 128 + sl * 8] = v;
  }
  __syncthreads();
#pragma unroll
  for (int rr = 0; rr < 4; ++rr) {
    const int task = tid + rr * 256;
    const int dr = task >> 3, c = task & 7;   // output row d=dr, s-chunk c
    u16x8 o;
#pragma unroll
    for (int e = 0; e < 8; ++e) {
      const int s = c * 8 + e;
      const int sl = (vslot(s, dr >> 3 & 7) | ((dr >> 3) & 8));
      o[e] = Vs[s * 128 + sl * 8 + (dr & 7)];
    }
    *(u16x8*)(Vt + (size_t)(bh * DD + dr) * SS + s0 + c * 8) = o;
  }
}

// ---------------- causal flash attention, paired q-tiles, dbuf K/V^T ----------------
__device__ __forceinline__ void softmax_pv(f32x4 s4[4], bool diag, int qrl0,
                                           float m_run[4], float l_run[4],
                                           f32x4 oacc[8], const u16* vtb,
                                           u16* psw, int quad, int l15) {
  const float SCL = 0.12751742904630190f;  // (1/sqrt(128)) * log2(e)
  float pv[4][4];
  float mx[4] = {-3e38f, -3e38f, -3e38f, -3e38f};
#pragma unroll
  for (int jt = 0; jt < 4; ++jt)
#pragma unroll
    for (int r = 0; r < 4; ++r) {
      float sv = s4[jt][r] * SCL;
      if (diag && (jt * 16 + l15) > (qrl0 + r)) sv = -3e38f;
      pv[jt][r] = sv;
      mx[r] = fmaxf(mx[r], sv);
    }
#pragma unroll
  for (int r = 0; r < 4; ++r) {
    mx[r] = fmaxf(mx[r], __shfl_xor(mx[r], 1));
    mx[r] = fmaxf(mx[r], __shfl_xor(mx[r], 2));
    mx[r] = fmaxf(mx[r], __shfl_xor(mx[r], 4));
    mx[r] = fmaxf(mx[r], __shfl_xor(mx[r], 8));
  }
  float al[4];
#pragma unroll
  for (int r = 0; r < 4; ++r) {
    const float mnew = fmaxf(m_run[r], mx[r]);
    al[r] = exp2f(m_run[r] - mnew);
    m_run[r] = mnew;
  }
  float rs[4] = {0.f, 0.f, 0.f, 0.f};
#pragma unroll
  for (int jt = 0; jt < 4; ++jt)
#pragma unroll
    for (int r = 0; r < 4; ++r) {
      const float pp = exp2f(pv[jt][r] - m_run[r]);
      pv[jt][r] = pp;
      rs[r] += pp;
    }
#pragma unroll
  for (int r = 0; r < 4; ++r) {
    rs[r] += __shfl_xor(rs[r], 1);
    rs[r] += __shfl_xor(rs[r], 2);
    rs[r] += __shfl_xor(rs[r], 4);
    rs[r] += __shfl_xor(rs[r], 8);
    l_run[r] = l_run[r] * al[r] + rs[r];
  }
#pragma unroll
  for (int jn = 0; jn < 8; ++jn)
#pragma unroll
    for (int r = 0; r < 4; ++r) oacc[jn][r] *= al[r];
#pragma unroll
  for (int jt = 0; jt < 4; ++jt)
#pragma unroll
    for (int r = 0; r < 4; ++r) {
      const int qr = quad * 4 + r, key = jt * 16 + l15;
      psw[qr * 64 + (((key >> 3) ^ (qr & 7)) << 3) + (key & 7)] = f2bf(pv[jt][r]);
    }
  __threadfence_block();
#pragma unroll
  for (int t = 0; t < 2; ++t) {
    const int gg = t * 4 + quad;
    bf16x8 pf = *(const bf16x8*)&psw[l15 * 64 + ((gg ^ (l15 & 7)) << 3)];
#pragma unroll
    for (int jn = 0; jn < 8; ++jn) {
      const int nd = jn * 16 + l15;
      bf16x8 vf = *(const bf16x8*)&vtb[nd * 64 + ((gg ^ (nd & 7)) << 3)];
      oacc[jn] = __builtin_amdgcn_mfma_f32_16x16x32_bf16(pf, vf, oacc[jn], 0, 0, 0);
    }
  }
}

__global__ __launch_bounds__(256, 2) void attn_kernel(const u16* __restrict__ Q,
                                                      const u16* __restrict__ Kg,
                                                      const u16* __restrict__ Vtg,
                                                      u16* __restrict__ ctx) {
  __shared__ __align__(16) u16 Ks[2][64 * 128];
  __shared__ __align__(16) u16 Vt[2][128 * 64];
  __shared__ __align__(16) u16 Ps[4][16 * 64];
  const int tid = threadIdx.x;
  const int wave = tid >> 6, lane = tid & 63;
  const int l15 = lane & 15, quad = lane >> 4;
  const int p = blockIdx.x, h = blockIdx.y, b = blockIdx.z;
  const int qlo = p, qhi = 31 - p;          // paired q-tiles: equal work per block
  const size_t bh = (size_t)(b * NHH + h);
  const u16* Qp = Q + bh * ((size_t)SS * DD);
  const u16* Kp = Kg + bh * ((size_t)SS * DD);
  const u16* Vp = Vtg + bh * ((size_t)DD * SS);

  bf16x8 qfl[4], qfh[4];
  {
    const u16* ql = Qp + (size_t)(qlo * 64 + wave * 16 + l15) * DD + quad * 8;
    const u16* qh = Qp + (size_t)(qhi * 64 + wave * 16 + l15) * DD + quad * 8;
#pragma unroll
    for (int t = 0; t < 4; ++t) {
      qfl[t] = *(const bf16x8*)(ql + t * 32);
      qfh[t] = *(const bf16x8*)(qh + t * 32);
    }
  }

  f32x4 oal[8] = {}, oah[8] = {};
  float ml[4] = {-3e38f, -3e38f, -3e38f, -3e38f};
  float mh[4] = {-3e38f, -3e38f, -3e38f, -3e38f};
  float ll[4] = {0.f, 0.f, 0.f, 0.f}, lh[4] = {0.f, 0.f, 0.f, 0.f};

  // stage k-tile kt into buf: K rows [key][d] + V^T rows [d][key], both coalesced 16B/lane
  auto stage = [&](int kt, int bufi) {
    const int k0 = kt * 64;
#pragma unroll
    for (int i = 0; i < 4; ++i) {
      const int g = wave * 4 + i;
      const int r = g * 4 + quad;
      const int c = l15 ^ (r & 15);
      gll16(Kp + (size_t)(k0 + r) * DD + c * 8, &Ks[bufi][g * 512]);
    }
#pragma unroll
    for (int i = 0; i < 4; ++i) {
      const int g = wave * 4 + i;
      const int d = g * 8 + (lane >> 3);
      const int c = (lane & 7) ^ (d & 7);
      gll16(Vp + (size_t)d * SS + k0 + c * 8, &Vt[bufi][g * 512]);
    }
  };

  stage(0, 0);
  const int qrl0 = wave * 16 + quad * 4;
  for (int kt = 0; kt <= qhi; ++kt) {
    __syncthreads();                       // buf[kt&1] ready (drains prefetch too)
    const u16* ksb = Ks[kt & 1];
    const u16* vtb = Vt[kt & 1];
    if (kt < qhi) stage(kt + 1, (kt + 1) & 1);  // in flight during compute
    const bool lo = (kt <= qlo);

    f32x4 sh4[4] = {}, sl4[4] = {};
#pragma unroll
    for (int t = 0; t < 4; ++t)
#pragma unroll
      for (int jt = 0; jt < 4; ++jt) {
        const int key = jt * 16 + l15;
        bf16x8 kf = *(const bf16x8*)&ksb[key * 128 + (((t * 4 + quad) ^ (key & 15)) << 3)];
        sh4[jt] = __builtin_amdgcn_mfma_f32_16x16x32_bf16(qfh[t], kf, sh4[jt], 0, 0, 0);
        if (lo) sl4[jt] = __builtin_amdgcn_mfma_f32_16x16x32_bf16(qfl[t], kf, sl4[jt], 0, 0, 0);
      }

    softmax_pv(sh4, kt == qhi, qrl0, mh, lh, oah, vtb, Ps[wave], quad, l15);
    if (lo) softmax_pv(sl4, kt == qlo, qrl0, ml, ll, oal, vtb, Ps[wave], quad, l15);
  }

  float invh[4], invl[4];
#pragma unroll
  for (int r = 0; r < 4; ++r) { invh[r] = 1.0f / lh[r]; invl[r] = 1.0f / ll[r]; }
#pragma unroll
  for (int jn = 0; jn < 8; ++jn)
#pragma unroll
    for (int r = 0; r < 4; ++r) {
      const int col = h * DD + jn * 16 + l15;
      const int rh = qhi * 64 + qrl0 + r;
      const int rl = qlo * 64 + qrl0 + r;
      ctx[(size_t)(b * SS + rh) * HH + col] = f2bf(oah[jn][r] * invh[r]);
      ctx[(size_t)(b * SS + rl) * HH + col] = f2bf(oal[jn][r] * invl[r]);
    }
}

// ---------------- launch ----------------
extern "C" void kernel_launch(void* const* d_in, const int* in_sizes, int n_in,
                              void* d_out, int out_size, void* d_ws, size_t ws_size,
                              hipStream_t stream) {
  (void)in_sizes; (void)n_in; (void)ws_size;
  const float* hidden = (const float*)d_in[0];
  const float* ln1w = (const float*)d_in[2];
  const float* ln1b = (const float*)d_in[3];
  const float* wqkv = (const float*)d_in[4];
  const float* bqkv = (const float*)d_in[5];
  const float* wdense = (const float*)d_in[6];
  const float* bdense = (const float*)d_in[7];
  const float* ln2w = (const float*)d_in[8];
  const float* ln2b = (const float*)d_in[9];
  const float* w1 = (const float*)d_in[10];
  const float* b1 = (const float*)d_in[11];
  const float* w2 = (const float*)d_in[12];
  const float* b2 = (const float*)d_in[13];

  char* ws = (char*)d_ws;
  size_t off = 0;
  auto alloc = [&](size_t elems) {
    u16* p = (u16*)(ws + off);
    off += ((elems * 2 + 255) & ~(size_t)255);
    return p;
  };
  u16* wqkvbf = alloc((size_t)3 * HH * HH);
  u16* wdbf   = alloc((size_t)HH * HH);
  u16* w1bf   = alloc((size_t)FFF * HH);
  u16* w2bf   = alloc((size_t)HH * FFF);
  u16* xbf    = alloc((size_t)MM * HH);
  u16* ctx    = alloc((size_t)MM * HH);
  u16* big    = alloc((size_t)MM * 3 * HH + 3 * (size_t)BB * NHH * SS * DD);
  u16* qkvbuf = big;
  u16* Qr = big + (size_t)MM * 3 * HH;
  u16* Kr = Qr + (size_t)BB * NHH * SS * DD;
  u16* Vtg = Kr + (size_t)BB * NHH * SS * DD;   // V^T [B*NH, D, S]
  u16* inter = big;                              // aliases qkv+Qr (dead by FF1)

  cvt_bf16<<<(3 * HH * HH) / 1024, 256, 0, stream>>>(wqkv, wqkvbf, 3 * HH * HH);
  cvt_bf16<<<(HH * HH) / 1024, 256, 0, stream>>>(wdense, wdbf, HH * HH);
  cvt_bf16<<<(FFF * HH) / 1024, 256, 0, stream>>>(w1, w1bf, FFF * HH);
  cvt_bf16<<<(HH * FFF) / 1024, 256, 0, stream>>>(w2, w2bf, HH * FFF);

  ln_bf16<<<MM, 256, 0, stream>>>(hidden, ln1w, ln1b, xbf);
  gemm_bt<0><<<dim3(MM / 128, (3 * HH) / 128), 256, 0, stream>>>(
      xbf, wqkvbf, bqkv, nullptr, qkvbuf, MM, 3 * HH, HH);
  rope_kernel<<<dim3(SS / 4, NHH, BB), 256, 0, stream>>>(qkvbuf, Qr, Kr);
  vtrans<<<dim3(SS / 64, BB * NHH), 256, 0, stream>>>(qkvbuf, Vtg);
  attn_kernel<<<dim3(16, NHH, BB), 256, 0, stream>>>(Qr, Kr, Vtg, ctx);
  gemm_bt<1><<<dim3(MM / 128, HH / 128), 256, 0, stream>>>(
      ctx, wdbf, bdense, hidden, d_out, MM, HH, HH);
  ln_bf16<<<MM, 256, 0, stream>>>((const float*)d_out, ln2w, ln2b, xbf);
  gemm_bt<2><<<dim3(MM / 128, FFF / 128), 256, 0, stream>>>(
      xbf, w1bf, b1, nullptr, inter, MM, FFF, HH);
  gemm_bt<1><<<dim3(MM / 128, HH / 128), 256, 0, stream>>>(
      inter, w2bf, b2, (const float*)d_out, d_out, MM, HH, FFF);

  const size_t hid_elems = (size_t)MM * HH;
  if ((size_t)out_size > hid_elems)
    hipMemsetAsync((char*)d_out + hid_elems * 4, 0,
                   ((size_t)out_size - hid_elems) * 4, stream);
}

// Round 3
// 923.488 us; speedup vs baseline: 1.3166x; 1.0314x over previous
//
#include <hip/hip_runtime.h>
#include <math.h>

typedef unsigned short u16;
typedef unsigned int u32;
typedef __attribute__((ext_vector_type(8))) __bf16 bf16x8;
typedef __attribute__((ext_vector_type(4))) float f32x4;
typedef __attribute__((ext_vector_type(8))) u16 u16x8;
typedef __attribute__((ext_vector_type(4))) u16 u16x4;

#define BB 2
#define SS 2048
#define HH 2048
#define NHH 16
#define DD 128
#define FFF 8192
#define MM (BB * SS)

__device__ __forceinline__ u16 f2bf(float f) {
  u32 u = __float_as_uint(f);
  u32 r = (u + 0x7FFFu + ((u >> 16) & 1u)) >> 16;
  return (u16)r;
}
__device__ __forceinline__ float b2f(u16 h) {
  return __uint_as_float(((u32)h) << 16);
}
__device__ __forceinline__ void gll16(const void* g, void* l) {
  __builtin_amdgcn_global_load_lds((const __attribute__((address_space(1))) void*)g,
                                   (__attribute__((address_space(3))) void*)l, 16, 0, 0);
}

// ---------------- batched fp32 -> bf16 convert (all 4 weight mats, 1 launch) ----------------
struct CvtArgs {
  const float* src[4];
  u16* dst[4];
  int n[4];
};
__global__ __launch_bounds__(256) void cvt_all(CvtArgs a) {
  const int seg = blockIdx.y;
  const int i = (blockIdx.x * 256 + threadIdx.x) * 4;
  if (i + 3 < a.n[seg]) {
    f32x4 v = *(const f32x4*)(a.src[seg] + i);
    u16x4 o;
    o[0] = f2bf(v[0]); o[1] = f2bf(v[1]); o[2] = f2bf(v[2]); o[3] = f2bf(v[3]);
    *(u16x4*)(a.dst[seg] + i) = o;
  }
}

// ---------------- LayerNorm (fp32 in, bf16 out) ----------------
__global__ __launch_bounds__(256) void ln_bf16(const float* __restrict__ x,
                                               const float* __restrict__ w,
                                               const float* __restrict__ bsh,
                                               u16* __restrict__ out) {
  const int row = blockIdx.x, tid = threadIdx.x;
  const float* xr = x + (size_t)row * HH;
  f32x4 a = ((const f32x4*)xr)[tid * 2];
  f32x4 b = ((const f32x4*)xr)[tid * 2 + 1];
  float s = a[0] + a[1] + a[2] + a[3] + b[0] + b[1] + b[2] + b[3];
  float q = a[0]*a[0] + a[1]*a[1] + a[2]*a[2] + a[3]*a[3]
          + b[0]*b[0] + b[1]*b[1] + b[2]*b[2] + b[3]*b[3];
#pragma unroll
  for (int off = 32; off > 0; off >>= 1) {
    s += __shfl_down(s, off);
    q += __shfl_down(q, off);
  }
  __shared__ float red[8];
  const int wave = tid >> 6;
  if ((tid & 63) == 0) { red[wave] = s; red[4 + wave] = q; }
  __syncthreads();
  s = red[0] + red[1] + red[2] + red[3];
  q = red[4] + red[5] + red[6] + red[7];
  const float mean = s * (1.0f / HH);
  const float var = q * (1.0f / HH) - mean * mean;
  const float rstd = 1.0f / sqrtf(var + 1e-5f);
  f32x4 w0 = ((const f32x4*)w)[tid * 2];
  f32x4 w1 = ((const f32x4*)w)[tid * 2 + 1];
  f32x4 b0 = ((const f32x4*)bsh)[tid * 2];
  f32x4 b1 = ((const f32x4*)bsh)[tid * 2 + 1];
  u16x8 o;
#pragma unroll
  for (int i = 0; i < 4; ++i) o[i] = f2bf((a[i] - mean) * rstd * w0[i] + b0[i]);
#pragma unroll
  for (int i = 0; i < 4; ++i) o[4 + i] = f2bf((b[i] - mean) * rstd * w1[i] + b1[i]);
  *(u16x8*)(out + (size_t)row * HH + tid * 8) = o;
}

// ---------------- GEMM: C[M,N] = A[M,K](bf16) * B^T[N,K](bf16) + epilogue ----------------
// MODE 0: +bias -> bf16.  MODE 1: +bias+resid(f32) -> f32.  MODE 2: +bias, gelu -> bf16.
// DB=1: double-buffered LDS, one barrier/iter (for grid-limited dispatches).
template <int MODE, int DB>
__global__ __launch_bounds__(256) void gemm_bt(const u16* __restrict__ A,
                                               const u16* __restrict__ Bw,
                                               const float* __restrict__ bias,
                                               const float* resid, void* Cout,
                                               int M, int N, int K) {
  __shared__ __align__(16) u16 As[DB ? 2 : 1][128 * 64];
  __shared__ __align__(16) u16 Bs[DB ? 2 : 1][128 * 64];
  const int tid = threadIdx.x;
  const int wave = tid >> 6, lane = tid & 63;
  const int l15 = lane & 15, quad = lane >> 4;

  // XCD-aware remap: same-XCD blocks (lin%8) share a bn range whose B-tiles fit one XCD L2 (4MB)
  const int lin = blockIdx.y * gridDim.x + blockIdx.x;
  const int per = gridDim.y >> 3;          // N/128/8  (all N here are multiples of 1024)
  const int t = lin >> 3;
  const int bn = (lin & 7) * per + (t % per);
  const int bm = t / per;

  const int wm = (wave >> 1) << 6, wn = (wave & 1) << 6;

  f32x4 acc[4][4] = {};

  const int srow = (wave << 5) + (lane >> 3);
  const int sg = (lane & 7) ^ (lane >> 3);
  const u16* aptr = A + (size_t)(bm * 128 + srow) * K + sg * 8;
  const u16* bptr = Bw + (size_t)(bn * 128 + srow) * K + sg * 8;

  auto stage = [&](int buf) {
#pragma unroll
    for (int i = 0; i < 4; ++i)
      gll16(aptr + (size_t)i * 8 * K, &As[buf][(wave * 4 + i) * 512]);
#pragma unroll
    for (int i = 0; i < 4; ++i)
      gll16(bptr + (size_t)i * 8 * K, &Bs[buf][(wave * 4 + i) * 512]);
    aptr += 64; bptr += 64;
  };

  auto compute = [&](int buf) {
#pragma unroll
    for (int tt = 0; tt < 2; ++tt) {
      bf16x8 af[4], bfv[4];
#pragma unroll
      for (int i = 0; i < 4; ++i) {
        const int m = wm + i * 16 + l15;
        const int n = wn + i * 16 + l15;
        const int gi = tt * 4 + quad;
        af[i] = *(const bf16x8*)&As[buf][m * 64 + ((gi ^ (m & 7)) << 3)];
        bfv[i] = *(const bf16x8*)&Bs[buf][n * 64 + ((gi ^ (n & 7)) << 3)];
      }
#pragma unroll
      for (int i = 0; i < 4; ++i)
#pragma unroll
        for (int j = 0; j < 4; ++j)
          acc[i][j] = __builtin_amdgcn_mfma_f32_16x16x32_bf16(af[i], bfv[j], acc[i][j], 0, 0, 0);
    }
  };

  const int nk = K >> 6;
  if constexpr (DB) {
    stage(0);
    for (int kt = 0; kt < nk; ++kt) {
      __syncthreads();                 // buf kt&1 ready (waits prefetch vmcnt too)
      if (kt + 1 < nk) stage((kt + 1) & 1);
      compute(kt & 1);
    }
  } else {
    for (int kt = 0; kt < nk; ++kt) {
      stage(0);
      __syncthreads();
      compute(0);
      __syncthreads();
    }
  }

#pragma unroll
  for (int i = 0; i < 4; ++i) {
    const int row0 = bm * 128 + wm + i * 16 + quad * 4;
#pragma unroll
    for (int j = 0; j < 4; ++j) {
      const int col = bn * 128 + wn + j * 16 + l15;
      const float bv = bias[col];
#pragma unroll
      for (int r = 0; r < 4; ++r) {
        const size_t idx = (size_t)(row0 + r) * N + col;
        float v = acc[i][j][r] + bv;
        if constexpr (MODE == 0) {
          ((u16*)Cout)[idx] = f2bf(v);
        } else if constexpr (MODE == 1) {
          ((float*)Cout)[idx] = v + resid[idx];
        } else {
          v = 0.5f * v * (1.0f + erff(v * 0.70710678118654752f));
          ((u16*)Cout)[idx] = f2bf(v);
        }
      }
    }
  }
}

// ---------------- RoPE: qkv [B,S,NH*3D] -> Qr/Kr [B,NH,S,D] ----------------
__global__ __launch_bounds__(256) void rope_kernel(const u16* __restrict__ qkv,
                                                   u16* __restrict__ Qr,
                                                   u16* __restrict__ Kr) {
  const int tid = threadIdx.x;
  const int d = tid & 63;
  const int s = blockIdx.x * 4 + (tid >> 6);
  const int h = blockIdx.y, b = blockIdx.z;
  const u16* row = qkv + ((size_t)(b * SS + s)) * (3 * HH) + h * (3 * DD);
  const float q1 = b2f(row[d]),        q2 = b2f(row[d + 64]);
  const float k1 = b2f(row[DD + d]),   k2 = b2f(row[DD + d + 64]);
  const float inv = expf((float)d * -0.14391156830963714f);
  const float ang = (float)s * inv;
  const float cs = cosf(ang), sn = sinf(ang);
  const size_t o = ((size_t)(b * NHH + h) * SS + s) * DD;
  Qr[o + d]      = f2bf(q1 * cs - q2 * sn);
  Qr[o + d + 64] = f2bf(q2 * cs + q1 * sn);
  Kr[o + d]      = f2bf(k1 * cs - k2 * sn);
  Kr[o + d + 64] = f2bf(k2 * cs + k1 * sn);
}

// ---------------- V transpose: qkv V-slice -> Vt_g [B*NH, D, S] ----------------
__device__ __forceinline__ int vslot(int s, int chunk) {
  return chunk ^ (s & 7) ^ ((s >> 3) & 7);
}
__global__ __launch_bounds__(256) void vtrans(const u16* __restrict__ qkv,
                                              u16* __restrict__ Vt) {
  __shared__ __align__(16) u16 Vs[64 * 128];
  const int tid = threadIdx.x;
  const int s0 = blockIdx.x * 64;
  const int bh = blockIdx.y;
  const int b = bh >> 4, h = bh & 15;
  const u16* src = qkv + (size_t)(b * SS + s0) * (3 * HH) + h * (3 * DD) + 2 * DD;
#pragma unroll
  for (int rr = 0; rr < 4; ++rr) {
    const int task = tid + rr * 256;
    const int sr = task >> 4, c = task & 15;
    u16x8 v = *(const u16x8*)(src + (size_t)sr * (3 * HH) + c * 8);
    const int sl = (vslot(sr, c & 7) | (c & 8));
    *(u16x8*)&Vs[sr * 128 + sl * 8] = v;
  }
  __syncthreads();
#pragma unroll
  for (int rr = 0; rr < 4; ++rr) {
    const int task = tid + rr * 256;
    const int dr = task >> 3, c = task & 7;
    u16x8 o;
#pragma unroll
    for (int e = 0; e < 8; ++e) {
      const int s = c * 8 + e;
      const int sl = (vslot(s, dr >> 3 & 7) | ((dr >> 3) & 8));
      o[e] = Vs[s * 128 + sl * 8 + (dr & 7)];
    }
    *(u16x8*)(Vt + (size_t)(bh * DD + dr) * SS + s0 + c * 8) = o;
  }
}

// ---------------- causal flash attention, paired q-tiles, dbuf K/V^T ----------------
__device__ __forceinline__ void softmax_pv(f32x4 s4[4], bool diag, int qrl0,
                                           float m_run[4], float l_run[4],
                                           f32x4 oacc[8], const u16* vtb,
                                           u16* psw, int quad, int l15) {
  const float SCL = 0.12751742904630190f;  // (1/sqrt(128)) * log2(e)
  float pv[4][4];
  float mx[4] = {-3e38f, -3e38f, -3e38f, -3e38f};
#pragma unroll
  for (int jt = 0; jt < 4; ++jt)
#pragma unroll
    for (int r = 0; r < 4; ++r) {
      float sv = s4[jt][r] * SCL;
      if (diag && (jt * 16 + l15) > (qrl0 + r)) sv = -3e38f;
      pv[jt][r] = sv;
      mx[r] = fmaxf(mx[r], sv);
    }
#pragma unroll
  for (int r = 0; r < 4; ++r) {
    mx[r] = fmaxf(mx[r], __shfl_xor(mx[r], 1));
    mx[r] = fmaxf(mx[r], __shfl_xor(mx[r], 2));
    mx[r] = fmaxf(mx[r], __shfl_xor(mx[r], 4));
    mx[r] = fmaxf(mx[r], __shfl_xor(mx[r], 8));
  }
  float al[4];
#pragma unroll
  for (int r = 0; r < 4; ++r) {
    const float mnew = fmaxf(m_run[r], mx[r]);
    al[r] = exp2f(m_run[r] - mnew);
    m_run[r] = mnew;
  }
  float rs[4] = {0.f, 0.f, 0.f, 0.f};
#pragma unroll
  for (int jt = 0; jt < 4; ++jt)
#pragma unroll
    for (int r = 0; r < 4; ++r) {
      const float pp = exp2f(pv[jt][r] - m_run[r]);
      pv[jt][r] = pp;
      rs[r] += pp;
    }
#pragma unroll
  for (int r = 0; r < 4; ++r) {
    rs[r] += __shfl_xor(rs[r], 1);
    rs[r] += __shfl_xor(rs[r], 2);
    rs[r] += __shfl_xor(rs[r], 4);
    rs[r] += __shfl_xor(rs[r], 8);
    l_run[r] = l_run[r] * al[r] + rs[r];
  }
#pragma unroll
  for (int jn = 0; jn < 8; ++jn)
#pragma unroll
    for (int r = 0; r < 4; ++r) oacc[jn][r] *= al[r];
#pragma unroll
  for (int jt = 0; jt < 4; ++jt)
#pragma unroll
    for (int r = 0; r < 4; ++r) {
      const int qr = quad * 4 + r, key = jt * 16 + l15;
      psw[qr * 64 + (((key >> 3) ^ (qr & 7)) << 3) + (key & 7)] = f2bf(pv[jt][r]);
    }
  __threadfence_block();
#pragma unroll
  for (int t = 0; t < 2; ++t) {
    const int gg = t * 4 + quad;
    bf16x8 pf = *(const bf16x8*)&psw[l15 * 64 + ((gg ^ (l15 & 7)) << 3)];
#pragma unroll
    for (int jn = 0; jn < 8; ++jn) {
      const int nd = jn * 16 + l15;
      bf16x8 vf = *(const bf16x8*)&vtb[nd * 64 + ((gg ^ (nd & 7)) << 3)];
      oacc[jn] = __builtin_amdgcn_mfma_f32_16x16x32_bf16(pf, vf, oacc[jn], 0, 0, 0);
    }
  }
}

__global__ __launch_bounds__(256, 2) void attn_kernel(const u16* __restrict__ Q,
                                                      const u16* __restrict__ Kg,
                                                      const u16* __restrict__ Vtg,
                                                      u16* __restrict__ ctx) {
  __shared__ __align__(16) u16 Ks[2][64 * 128];
  __shared__ __align__(16) u16 Vt[2][128 * 64];
  __shared__ __align__(16) u16 Ps[4][16 * 64];
  const int tid = threadIdx.x;
  const int wave = tid >> 6, lane = tid & 63;
  const int l15 = lane & 15, quad = lane >> 4;
  const int p = blockIdx.x, h = blockIdx.y, b = blockIdx.z;
  const int qlo = p, qhi = 31 - p;
  const size_t bh = (size_t)(b * NHH + h);
  const u16* Qp = Q + bh * ((size_t)SS * DD);
  const u16* Kp = Kg + bh * ((size_t)SS * DD);
  const u16* Vp = Vtg + bh * ((size_t)DD * SS);

  bf16x8 qfl[4], qfh[4];
  {
    const u16* ql = Qp + (size_t)(qlo * 64 + wave * 16 + l15) * DD + quad * 8;
    const u16* qh = Qp + (size_t)(qhi * 64 + wave * 16 + l15) * DD + quad * 8;
#pragma unroll
    for (int t = 0; t < 4; ++t) {
      qfl[t] = *(const bf16x8*)(ql + t * 32);
      qfh[t] = *(const bf16x8*)(qh + t * 32);
    }
  }

  f32x4 oal[8] = {}, oah[8] = {};
  float ml[4] = {-3e38f, -3e38f, -3e38f, -3e38f};
  float mh[4] = {-3e38f, -3e38f, -3e38f, -3e38f};
  float ll[4] = {0.f, 0.f, 0.f, 0.f}, lh[4] = {0.f, 0.f, 0.f, 0.f};

  auto stage = [&](int kt, int bufi) {
    const int k0 = kt * 64;
#pragma unroll
    for (int i = 0; i < 4; ++i) {
      const int g = wave * 4 + i;
      const int r = g * 4 + quad;
      const int c = l15 ^ (r & 15);
      gll16(Kp + (size_t)(k0 + r) * DD + c * 8, &Ks[bufi][g * 512]);
    }
#pragma unroll
    for (int i = 0; i < 4; ++i) {
      const int g = wave * 4 + i;
      const int d = g * 8 + (lane >> 3);
      const int c = (lane & 7) ^ (d & 7);
      gll16(Vp + (size_t)d * SS + k0 + c * 8, &Vt[bufi][g * 512]);
    }
  };

  stage(0, 0);
  const int qrl0 = wave * 16 + quad * 4;
  for (int kt = 0; kt <= qhi; ++kt) {
    __syncthreads();
    const u16* ksb = Ks[kt & 1];
    const u16* vtb = Vt[kt & 1];
    if (kt < qhi) stage(kt + 1, (kt + 1) & 1);
    const bool lo = (kt <= qlo);

    f32x4 sh4[4] = {}, sl4[4] = {};
#pragma unroll
    for (int t = 0; t < 4; ++t)
#pragma unroll
      for (int jt = 0; jt < 4; ++jt) {
        const int key = jt * 16 + l15;
        bf16x8 kf = *(const bf16x8*)&ksb[key * 128 + (((t * 4 + quad) ^ (key & 15)) << 3)];
        sh4[jt] = __builtin_amdgcn_mfma_f32_16x16x32_bf16(qfh[t], kf, sh4[jt], 0, 0, 0);
        if (lo) sl4[jt] = __builtin_amdgcn_mfma_f32_16x16x32_bf16(qfl[t], kf, sl4[jt], 0, 0, 0);
      }

    softmax_pv(sh4, kt == qhi, qrl0, mh, lh, oah, vtb, Ps[wave], quad, l15);
    if (lo) softmax_pv(sl4, kt == qlo, qrl0, ml, ll, oal, vtb, Ps[wave], quad, l15);
  }

  float invh[4], invl[4];
#pragma unroll
  for (int r = 0; r < 4; ++r) { invh[r] = 1.0f / lh[r]; invl[r] = 1.0f / ll[r]; }
#pragma unroll
  for (int jn = 0; jn < 8; ++jn)
#pragma unroll
    for (int r = 0; r < 4; ++r) {
      const int col = h * DD + jn * 16 + l15;
      const int rh = qhi * 64 + qrl0 + r;
      const int rl = qlo * 64 + qrl0 + r;
      ctx[(size_t)(b * SS + rh) * HH + col] = f2bf(oah[jn][r] * invh[r]);
      ctx[(size_t)(b * SS + rl) * HH + col] = f2bf(oal[jn][r] * invl[r]);
    }
}

// ---------------- launch ----------------
extern "C" void kernel_launch(void* const* d_in, const int* in_sizes, int n_in,
                              void* d_out, int out_size, void* d_ws, size_t ws_size,
                              hipStream_t stream) {
  (void)in_sizes; (void)n_in; (void)ws_size;
  const float* hidden = (const float*)d_in[0];
  const float* ln1w = (const float*)d_in[2];
  const float* ln1b = (const float*)d_in[3];
  const float* wqkv = (const float*)d_in[4];
  const float* bqkv = (const float*)d_in[5];
  const float* wdense = (const float*)d_in[6];
  const float* bdense = (const float*)d_in[7];
  const float* ln2w = (const float*)d_in[8];
  const float* ln2b = (const float*)d_in[9];
  const float* w1 = (const float*)d_in[10];
  const float* b1 = (const float*)d_in[11];
  const float* w2 = (const float*)d_in[12];
  const float* b2 = (const float*)d_in[13];

  char* ws = (char*)d_ws;
  size_t off = 0;
  auto alloc = [&](size_t elems) {
    u16* p = (u16*)(ws + off);
    off += ((elems * 2 + 255) & ~(size_t)255);
    return p;
  };
  u16* wqkvbf = alloc((size_t)3 * HH * HH);
  u16* wdbf   = alloc((size_t)HH * HH);
  u16* w1bf   = alloc((size_t)FFF * HH);
  u16* w2bf   = alloc((size_t)HH * FFF);
  u16* xbf    = alloc((size_t)MM * HH);
  u16* ctx    = alloc((size_t)MM * HH);
  u16* big    = alloc((size_t)MM * 3 * HH + 3 * (size_t)BB * NHH * SS * DD);
  u16* qkvbuf = big;
  u16* Qr = big + (size_t)MM * 3 * HH;
  u16* Kr = Qr + (size_t)BB * NHH * SS * DD;
  u16* Vtg = Kr + (size_t)BB * NHH * SS * DD;
  u16* inter = big;                              // aliases qkv+Qr (dead by FF1)

  CvtArgs ca;
  ca.src[0] = wqkv;   ca.dst[0] = wqkvbf; ca.n[0] = 3 * HH * HH;
  ca.src[1] = wdense; ca.dst[1] = wdbf;   ca.n[1] = HH * HH;
  ca.src[2] = w1;     ca.dst[2] = w1bf;   ca.n[2] = FFF * HH;
  ca.src[3] = w2;     ca.dst[3] = w2bf;   ca.n[3] = HH * FFF;
  cvt_all<<<dim3((FFF * HH) / 1024, 4), 256, 0, stream>>>(ca);

  ln_bf16<<<MM, 256, 0, stream>>>(hidden, ln1w, ln1b, xbf);
  gemm_bt<0, 0><<<dim3(MM / 128, (3 * HH) / 128), 256, 0, stream>>>(
      xbf, wqkvbf, bqkv, nullptr, qkvbuf, MM, 3 * HH, HH);
  rope_kernel<<<dim3(SS / 4, NHH, BB), 256, 0, stream>>>(qkvbuf, Qr, Kr);
  vtrans<<<dim3(SS / 64, BB * NHH), 256, 0, stream>>>(qkvbuf, Vtg);
  attn_kernel<<<dim3(16, NHH, BB), 256, 0, stream>>>(Qr, Kr, Vtg, ctx);
  gemm_bt<1, 1><<<dim3(MM / 128, HH / 128), 256, 0, stream>>>(
      ctx, wdbf, bdense, hidden, d_out, MM, HH, HH);
  ln_bf16<<<MM, 256, 0, stream>>>((const float*)d_out, ln2w, ln2b, xbf);
  gemm_bt<2, 0><<<dim3(MM / 128, FFF / 128), 256, 0, stream>>>(
      xbf, w1bf, b1, nullptr, inter, MM, FFF, HH);
  gemm_bt<1, 1><<<dim3(MM / 128, HH / 128), 256, 0, stream>>>(
      inter, w2bf, b2, (const float*)d_out, d_out, MM, HH, FFF);

  const size_t hid_elems = (size_t)MM * HH;
  if ((size_t)out_size > hid_elems)
    hipMemsetAsync((char*)d_out + hid_elems * 4, 0,
                   ((size_t)out_size - hid_elems) * 4, stream);
}

// Round 4
// 921.668 us; speedup vs baseline: 1.3192x; 1.0020x over previous
//
#include <hip/hip_runtime.h>
#include <math.h>

typedef unsigned short u16;
typedef unsigned int u32;
typedef __attribute__((ext_vector_type(8))) __bf16 bf16x8;
typedef __attribute__((ext_vector_type(4))) float f32x4;
typedef __attribute__((ext_vector_type(8))) u16 u16x8;
typedef __attribute__((ext_vector_type(4))) u16 u16x4;

#define BB 2
#define SS 2048
#define HH 2048
#define NHH 16
#define DD 128
#define FFF 8192
#define MM (BB * SS)

__device__ __forceinline__ u16 f2bf(float f) {
  u32 u = __float_as_uint(f);
  u32 r = (u + 0x7FFFu + ((u >> 16) & 1u)) >> 16;
  return (u16)r;
}
__device__ __forceinline__ float b2f(u16 h) {
  return __uint_as_float(((u32)h) << 16);
}
__device__ __forceinline__ void gll16(const void* g, void* l) {
  __builtin_amdgcn_global_load_lds((const __attribute__((address_space(1))) void*)g,
                                   (__attribute__((address_space(3))) void*)l, 16, 0, 0);
}

// ---------------- batched fp32 -> bf16 convert (all 4 weight mats, 1 launch) ----------------
struct CvtArgs {
  const float* src[4];
  u16* dst[4];
  int n[4];
};
__global__ __launch_bounds__(256) void cvt_all(CvtArgs a) {
  const int seg = blockIdx.y;
  const int i = (blockIdx.x * 256 + threadIdx.x) * 4;
  if (i + 3 < a.n[seg]) {
    f32x4 v = *(const f32x4*)(a.src[seg] + i);
    u16x4 o;
    o[0] = f2bf(v[0]); o[1] = f2bf(v[1]); o[2] = f2bf(v[2]); o[3] = f2bf(v[3]);
    *(u16x4*)(a.dst[seg] + i) = o;
  }
}

// ---------------- LayerNorm (fp32 in, bf16 out) ----------------
__global__ __launch_bounds__(256) void ln_bf16(const float* __restrict__ x,
                                               const float* __restrict__ w,
                                               const float* __restrict__ bsh,
                                               u16* __restrict__ out) {
  const int row = blockIdx.x, tid = threadIdx.x;
  const float* xr = x + (size_t)row * HH;
  f32x4 a = ((const f32x4*)xr)[tid * 2];
  f32x4 b = ((const f32x4*)xr)[tid * 2 + 1];
  float s = a[0] + a[1] + a[2] + a[3] + b[0] + b[1] + b[2] + b[3];
  float q = a[0]*a[0] + a[1]*a[1] + a[2]*a[2] + a[3]*a[3]
          + b[0]*b[0] + b[1]*b[1] + b[2]*b[2] + b[3]*b[3];
#pragma unroll
  for (int off = 32; off > 0; off >>= 1) {
    s += __shfl_down(s, off);
    q += __shfl_down(q, off);
  }
  __shared__ float red[8];
  const int wave = tid >> 6;
  if ((tid & 63) == 0) { red[wave] = s; red[4 + wave] = q; }
  __syncthreads();
  s = red[0] + red[1] + red[2] + red[3];
  q = red[4] + red[5] + red[6] + red[7];
  const float mean = s * (1.0f / HH);
  const float var = q * (1.0f / HH) - mean * mean;
  const float rstd = 1.0f / sqrtf(var + 1e-5f);
  f32x4 w0 = ((const f32x4*)w)[tid * 2];
  f32x4 w1 = ((const f32x4*)w)[tid * 2 + 1];
  f32x4 b0 = ((const f32x4*)bsh)[tid * 2];
  f32x4 b1 = ((const f32x4*)bsh)[tid * 2 + 1];
  u16x8 o;
#pragma unroll
  for (int i = 0; i < 4; ++i) o[i] = f2bf((a[i] - mean) * rstd * w0[i] + b0[i]);
#pragma unroll
  for (int i = 0; i < 4; ++i) o[4 + i] = f2bf((b[i] - mean) * rstd * w1[i] + b1[i]);
  *(u16x8*)(out + (size_t)row * HH + tid * 8) = o;
}

// ---------------- GEMM: C[M,N] = A[M,K](bf16) * B^T[N,K](bf16) + epilogue ----------------
// MODE 0: +bias -> bf16.  MODE 1: +bias+resid(f32) -> f32.  MODE 2: +bias, gelu -> bf16.
// DB=1: double-buffered LDS, one barrier/iter (for grid-limited dispatches).
template <int MODE, int DB>
__global__ __launch_bounds__(256) void gemm_bt(const u16* __restrict__ A,
                                               const u16* __restrict__ Bw,
                                               const float* __restrict__ bias,
                                               const float* resid, void* Cout,
                                               int M, int N, int K) {
  __shared__ __align__(16) u16 As[DB ? 2 : 1][128 * 64];
  __shared__ __align__(16) u16 Bs[DB ? 2 : 1][128 * 64];
  const int tid = threadIdx.x;
  const int wave = tid >> 6, lane = tid & 63;
  const int l15 = lane & 15, quad = lane >> 4;
  const int bm = blockIdx.x, bn = blockIdx.y;   // natural order: x-fastest keeps
                                                // A-row tiles hot across bn sweep
                                                // (R3 XCD remap doubled FETCH — reverted)
  const int wm = (wave >> 1) << 6, wn = (wave & 1) << 6;

  f32x4 acc[4][4] = {};

  const int srow = (wave << 5) + (lane >> 3);
  const int sg = (lane & 7) ^ (lane >> 3);
  const u16* aptr = A + (size_t)(bm * 128 + srow) * K + sg * 8;
  const u16* bptr = Bw + (size_t)(bn * 128 + srow) * K + sg * 8;

  auto stage = [&](int buf) {
#pragma unroll
    for (int i = 0; i < 4; ++i)
      gll16(aptr + (size_t)i * 8 * K, &As[buf][(wave * 4 + i) * 512]);
#pragma unroll
    for (int i = 0; i < 4; ++i)
      gll16(bptr + (size_t)i * 8 * K, &Bs[buf][(wave * 4 + i) * 512]);
    aptr += 64; bptr += 64;
  };

  auto compute = [&](int buf) {
#pragma unroll
    for (int tt = 0; tt < 2; ++tt) {
      bf16x8 af[4], bfv[4];
#pragma unroll
      for (int i = 0; i < 4; ++i) {
        const int m = wm + i * 16 + l15;
        const int n = wn + i * 16 + l15;
        const int gi = tt * 4 + quad;
        af[i] = *(const bf16x8*)&As[buf][m * 64 + ((gi ^ (m & 7)) << 3)];
        bfv[i] = *(const bf16x8*)&Bs[buf][n * 64 + ((gi ^ (n & 7)) << 3)];
      }
#pragma unroll
      for (int i = 0; i < 4; ++i)
#pragma unroll
        for (int j = 0; j < 4; ++j)
          acc[i][j] = __builtin_amdgcn_mfma_f32_16x16x32_bf16(af[i], bfv[j], acc[i][j], 0, 0, 0);
    }
  };

  const int nk = K >> 6;
  if constexpr (DB) {
    stage(0);
    for (int kt = 0; kt < nk; ++kt) {
      __syncthreads();                 // buf kt&1 ready (waits prefetch vmcnt too)
      if (kt + 1 < nk) stage((kt + 1) & 1);
      compute(kt & 1);
    }
  } else {
    for (int kt = 0; kt < nk; ++kt) {
      stage(0);
      __syncthreads();
      compute(0);
      __syncthreads();
    }
  }

#pragma unroll
  for (int i = 0; i < 4; ++i) {
    const int row0 = bm * 128 + wm + i * 16 + quad * 4;
#pragma unroll
    for (int j = 0; j < 4; ++j) {
      const int col = bn * 128 + wn + j * 16 + l15;
      const float bv = bias[col];
#pragma unroll
      for (int r = 0; r < 4; ++r) {
        const size_t idx = (size_t)(row0 + r) * N + col;
        float v = acc[i][j][r] + bv;
        if constexpr (MODE == 0) {
          ((u16*)Cout)[idx] = f2bf(v);
        } else if constexpr (MODE == 1) {
          ((float*)Cout)[idx] = v + resid[idx];
        } else {
          v = 0.5f * v * (1.0f + erff(v * 0.70710678118654752f));
          ((u16*)Cout)[idx] = f2bf(v);
        }
      }
    }
  }
}

// ---------------- RoPE: qkv [B,S,NH*3D] -> Qr/Kr [B,NH,S,D] ----------------
__global__ __launch_bounds__(256) void rope_kernel(const u16* __restrict__ qkv,
                                                   u16* __restrict__ Qr,
                                                   u16* __restrict__ Kr) {
  const int tid = threadIdx.x;
  const int d = tid & 63;
  const int s = blockIdx.x * 4 + (tid >> 6);
  const int h = blockIdx.y, b = blockIdx.z;
  const u16* row = qkv + ((size_t)(b * SS + s)) * (3 * HH) + h * (3 * DD);
  const float q1 = b2f(row[d]),        q2 = b2f(row[d + 64]);
  const float k1 = b2f(row[DD + d]),   k2 = b2f(row[DD + d + 64]);
  const float inv = expf((float)d * -0.14391156830963714f);
  const float ang = (float)s * inv;
  const float cs = cosf(ang), sn = sinf(ang);
  const size_t o = ((size_t)(b * NHH + h) * SS + s) * DD;
  Qr[o + d]      = f2bf(q1 * cs - q2 * sn);
  Qr[o + d + 64] = f2bf(q2 * cs + q1 * sn);
  Kr[o + d]      = f2bf(k1 * cs - k2 * sn);
  Kr[o + d + 64] = f2bf(k2 * cs + k1 * sn);
}

// ---------------- V transpose: qkv V-slice -> Vt_g [B*NH, D, S] ----------------
__device__ __forceinline__ int vslot(int s, int chunk) {
  return chunk ^ (s & 7) ^ ((s >> 3) & 7);
}
__global__ __launch_bounds__(256) void vtrans(const u16* __restrict__ qkv,
                                              u16* __restrict__ Vt) {
  __shared__ __align__(16) u16 Vs[64 * 128];
  const int tid = threadIdx.x;
  const int s0 = blockIdx.x * 64;
  const int bh = blockIdx.y;
  const int b = bh >> 4, h = bh & 15;
  const u16* src = qkv + (size_t)(b * SS + s0) * (3 * HH) + h * (3 * DD) + 2 * DD;
#pragma unroll
  for (int rr = 0; rr < 4; ++rr) {
    const int task = tid + rr * 256;
    const int sr = task >> 4, c = task & 15;
    u16x8 v = *(const u16x8*)(src + (size_t)sr * (3 * HH) + c * 8);
    const int sl = (vslot(sr, c & 7) | (c & 8));
    *(u16x8*)&Vs[sr * 128 + sl * 8] = v;
  }
  __syncthreads();
#pragma unroll
  for (int rr = 0; rr < 4; ++rr) {
    const int task = tid + rr * 256;
    const int dr = task >> 3, c = task & 7;
    u16x8 o;
#pragma unroll
    for (int e = 0; e < 8; ++e) {
      const int s = c * 8 + e;
      const int sl = (vslot(s, dr >> 3 & 7) | ((dr >> 3) & 8));
      o[e] = Vs[s * 128 + sl * 8 + (dr & 7)];
    }
    *(u16x8*)(Vt + (size_t)(bh * DD + dr) * SS + s0 + c * 8) = o;
  }
}

// ---------------- causal flash attention, paired q-tiles, dbuf K/V^T ----------------
__device__ __forceinline__ void softmax_pv(f32x4 s4[4], bool diag, int qrl0,
                                           float m_run[4], float l_run[4],
                                           f32x4 oacc[8], const u16* vtb,
                                           u16* psw, int quad, int l15) {
  const float SCL = 0.12751742904630190f;  // (1/sqrt(128)) * log2(e)
  float pv[4][4];
  float mx[4] = {-3e38f, -3e38f, -3e38f, -3e38f};
#pragma unroll
  for (int jt = 0; jt < 4; ++jt)
#pragma unroll
    for (int r = 0; r < 4; ++r) {
      float sv = s4[jt][r] * SCL;
      if (diag && (jt * 16 + l15) > (qrl0 + r)) sv = -3e38f;
      pv[jt][r] = sv;
      mx[r] = fmaxf(mx[r], sv);
    }
#pragma unroll
  for (int r = 0; r < 4; ++r) {
    mx[r] = fmaxf(mx[r], __shfl_xor(mx[r], 1));
    mx[r] = fmaxf(mx[r], __shfl_xor(mx[r], 2));
    mx[r] = fmaxf(mx[r], __shfl_xor(mx[r], 4));
    mx[r] = fmaxf(mx[r], __shfl_xor(mx[r], 8));
  }
  float al[4];
#pragma unroll
  for (int r = 0; r < 4; ++r) {
    const float mnew = fmaxf(m_run[r], mx[r]);
    al[r] = exp2f(m_run[r] - mnew);
    m_run[r] = mnew;
  }
  float rs[4] = {0.f, 0.f, 0.f, 0.f};
#pragma unroll
  for (int jt = 0; jt < 4; ++jt)
#pragma unroll
    for (int r = 0; r < 4; ++r) {
      const float pp = exp2f(pv[jt][r] - m_run[r]);
      pv[jt][r] = pp;
      rs[r] += pp;
    }
#pragma unroll
  for (int r = 0; r < 4; ++r) {
    rs[r] += __shfl_xor(rs[r], 1);
    rs[r] += __shfl_xor(rs[r], 2);
    rs[r] += __shfl_xor(rs[r], 4);
    rs[r] += __shfl_xor(rs[r], 8);
    l_run[r] = l_run[r] * al[r] + rs[r];
  }
#pragma unroll
  for (int jn = 0; jn < 8; ++jn)
#pragma unroll
    for (int r = 0; r < 4; ++r) oacc[jn][r] *= al[r];
#pragma unroll
  for (int jt = 0; jt < 4; ++jt)
#pragma unroll
    for (int r = 0; r < 4; ++r) {
      const int qr = quad * 4 + r, key = jt * 16 + l15;
      psw[qr * 64 + (((key >> 3) ^ (qr & 7)) << 3) + (key & 7)] = f2bf(pv[jt][r]);
    }
  __threadfence_block();
#pragma unroll
  for (int t = 0; t < 2; ++t) {
    const int gg = t * 4 + quad;
    bf16x8 pf = *(const bf16x8*)&psw[l15 * 64 + ((gg ^ (l15 & 7)) << 3)];
#pragma unroll
    for (int jn = 0; jn < 8; ++jn) {
      const int nd = jn * 16 + l15;
      bf16x8 vf = *(const bf16x8*)&vtb[nd * 64 + ((gg ^ (nd & 7)) << 3)];
      oacc[jn] = __builtin_amdgcn_mfma_f32_16x16x32_bf16(pf, vf, oacc[jn], 0, 0, 0);
    }
  }
}

__global__ __launch_bounds__(256, 2) void attn_kernel(const u16* __restrict__ Q,
                                                      const u16* __restrict__ Kg,
                                                      const u16* __restrict__ Vtg,
                                                      u16* __restrict__ ctx) {
  __shared__ __align__(16) u16 Ks[2][64 * 128];
  __shared__ __align__(16) u16 Vt[2][128 * 64];
  __shared__ __align__(16) u16 Ps[4][16 * 64];
  const int tid = threadIdx.x;
  const int wave = tid >> 6, lane = tid & 63;
  const int l15 = lane & 15, quad = lane >> 4;
  const int p = blockIdx.x, h = blockIdx.y, b = blockIdx.z;
  const int qlo = p, qhi = 31 - p;
  const size_t bh = (size_t)(b * NHH + h);
  const u16* Qp = Q + bh * ((size_t)SS * DD);
  const u16* Kp = Kg + bh * ((size_t)SS * DD);
  const u16* Vp = Vtg + bh * ((size_t)DD * SS);

  bf16x8 qfl[4], qfh[4];
  {
    const u16* ql = Qp + (size_t)(qlo * 64 + wave * 16 + l15) * DD + quad * 8;
    const u16* qh = Qp + (size_t)(qhi * 64 + wave * 16 + l15) * DD + quad * 8;
#pragma unroll
    for (int t = 0; t < 4; ++t) {
      qfl[t] = *(const bf16x8*)(ql + t * 32);
      qfh[t] = *(const bf16x8*)(qh + t * 32);
    }
  }

  f32x4 oal[8] = {}, oah[8] = {};
  float ml[4] = {-3e38f, -3e38f, -3e38f, -3e38f};
  float mh[4] = {-3e38f, -3e38f, -3e38f, -3e38f};
  float ll[4] = {0.f, 0.f, 0.f, 0.f}, lh[4] = {0.f, 0.f, 0.f, 0.f};

  auto stage = [&](int kt, int bufi) {
    const int k0 = kt * 64;
#pragma unroll
    for (int i = 0; i < 4; ++i) {
      const int g = wave * 4 + i;
      const int r = g * 4 + quad;
      const int c = l15 ^ (r & 15);
      gll16(Kp + (size_t)(k0 + r) * DD + c * 8, &Ks[bufi][g * 512]);
    }
#pragma unroll
    for (int i = 0; i < 4; ++i) {
      const int g = wave * 4 + i;
      const int d = g * 8 + (lane >> 3);
      const int c = (lane & 7) ^ (d & 7);
      gll16(Vp + (size_t)d * SS + k0 + c * 8, &Vt[bufi][g * 512]);
    }
  };

  stage(0, 0);
  const int qrl0 = wave * 16 + quad * 4;
  for (int kt = 0; kt <= qhi; ++kt) {
    __syncthreads();
    const u16* ksb = Ks[kt & 1];
    const u16* vtb = Vt[kt & 1];
    if (kt < qhi) stage(kt + 1, (kt + 1) & 1);
    const bool lo = (kt <= qlo);

    f32x4 sh4[4] = {}, sl4[4] = {};
#pragma unroll
    for (int t = 0; t < 4; ++t)
#pragma unroll
      for (int jt = 0; jt < 4; ++jt) {
        const int key = jt * 16 + l15;
        bf16x8 kf = *(const bf16x8*)&ksb[key * 128 + (((t * 4 + quad) ^ (key & 15)) << 3)];
        sh4[jt] = __builtin_amdgcn_mfma_f32_16x16x32_bf16(qfh[t], kf, sh4[jt], 0, 0, 0);
        if (lo) sl4[jt] = __builtin_amdgcn_mfma_f32_16x16x32_bf16(qfl[t], kf, sl4[jt], 0, 0, 0);
      }

    softmax_pv(sh4, kt == qhi, qrl0, mh, lh, oah, vtb, Ps[wave], quad, l15);
    if (lo) softmax_pv(sl4, kt == qlo, qrl0, ml, ll, oal, vtb, Ps[wave], quad, l15);
  }

  float invh[4], invl[4];
#pragma unroll
  for (int r = 0; r < 4; ++r) { invh[r] = 1.0f / lh[r]; invl[r] = 1.0f / ll[r]; }
#pragma unroll
  for (int jn = 0; jn < 8; ++jn)
#pragma unroll
    for (int r = 0; r < 4; ++r) {
      const int col = h * DD + jn * 16 + l15;
      const int rh = qhi * 64 + qrl0 + r;
      const int rl = qlo * 64 + qrl0 + r;
      ctx[(size_t)(b * SS + rh) * HH + col] = f2bf(oah[jn][r] * invh[r]);
      ctx[(size_t)(b * SS + rl) * HH + col] = f2bf(oal[jn][r] * invl[r]);
    }
}

// ---------------- launch ----------------
extern "C" void kernel_launch(void* const* d_in, const int* in_sizes, int n_in,
                              void* d_out, int out_size, void* d_ws, size_t ws_size,
                              hipStream_t stream) {
  (void)in_sizes; (void)n_in; (void)ws_size;
  const float* hidden = (const float*)d_in[0];
  const float* ln1w = (const float*)d_in[2];
  const float* ln1b = (const float*)d_in[3];
  const float* wqkv = (const float*)d_in[4];
  const float* bqkv = (const float*)d_in[5];
  const float* wdense = (const float*)d_in[6];
  const float* bdense = (const float*)d_in[7];
  const float* ln2w = (const float*)d_in[8];
  const float* ln2b = (const float*)d_in[9];
  const float* w1 = (const float*)d_in[10];
  const float* b1 = (const float*)d_in[11];
  const float* w2 = (const float*)d_in[12];
  const float* b2 = (const float*)d_in[13];

  char* ws = (char*)d_ws;
  size_t off = 0;
  auto alloc = [&](size_t elems) {
    u16* p = (u16*)(ws + off);
    off += ((elems * 2 + 255) & ~(size_t)255);
    return p;
  };
  u16* wqkvbf = alloc((size_t)3 * HH * HH);
  u16* wdbf   = alloc((size_t)HH * HH);
  u16* w1bf   = alloc((size_t)FFF * HH);
  u16* w2bf   = alloc((size_t)HH * FFF);
  u16* xbf    = alloc((size_t)MM * HH);
  u16* ctx    = alloc((size_t)MM * HH);
  u16* big    = alloc((size_t)MM * 3 * HH + 3 * (size_t)BB * NHH * SS * DD);
  u16* qkvbuf = big;
  u16* Qr = big + (size_t)MM * 3 * HH;
  u16* Kr = Qr + (size_t)BB * NHH * SS * DD;
  u16* Vtg = Kr + (size_t)BB * NHH * SS * DD;
  u16* inter = big;                              // aliases qkv+Qr (dead by FF1)

  CvtArgs ca;
  ca.src[0] = wqkv;   ca.dst[0] = wqkvbf; ca.n[0] = 3 * HH * HH;
  ca.src[1] = wdense; ca.dst[1] = wdbf;   ca.n[1] = HH * HH;
  ca.src[2] = w1;     ca.dst[2] = w1bf;   ca.n[2] = FFF * HH;
  ca.src[3] = w2;     ca.dst[3] = w2bf;   ca.n[3] = HH * FFF;
  cvt_all<<<dim3((FFF * HH) / 1024, 4), 256, 0, stream>>>(ca);

  ln_bf16<<<MM, 256, 0, stream>>>(hidden, ln1w, ln1b, xbf);
  gemm_bt<0, 0><<<dim3(MM / 128, (3 * HH) / 128), 256, 0, stream>>>(
      xbf, wqkvbf, bqkv, nullptr, qkvbuf, MM, 3 * HH, HH);
  rope_kernel<<<dim3(SS / 4, NHH, BB), 256, 0, stream>>>(qkvbuf, Qr, Kr);
  vtrans<<<dim3(SS / 64, BB * NHH), 256, 0, stream>>>(qkvbuf, Vtg);
  attn_kernel<<<dim3(16, NHH, BB), 256, 0, stream>>>(Qr, Kr, Vtg, ctx);
  gemm_bt<1, 1><<<dim3(MM / 128, HH / 128), 256, 0, stream>>>(
      ctx, wdbf, bdense, hidden, d_out, MM, HH, HH);
  ln_bf16<<<MM, 256, 0, stream>>>((const float*)d_out, ln2w, ln2b, xbf);
  gemm_bt<2, 0><<<dim3(MM / 128, FFF / 128), 256, 0, stream>>>(
      xbf, w1bf, b1, nullptr, inter, MM, FFF, HH);
  gemm_bt<1, 1><<<dim3(MM / 128, HH / 128), 256, 0, stream>>>(
      inter, w2bf, b2, (const float*)d_out, d_out, MM, HH, FFF);

  const size_t hid_elems = (size_t)MM * HH;
  if ((size_t)out_size > hid_elems)
    hipMemsetAsync((char*)d_out + hid_elems * 4, 0,
                   ((size_t)out_size - hid_elems) * 4, stream);
}